// Round 6
// baseline (434.663 us; speedup 1.0000x reference)
//
#include <hip/hip_runtime.h>
#include <math.h>

#define NROWS 8192
#define DDIM  2048
#define NEXP  4096
#define TK    8
#define KSPLIT 4
#define KRANGE (DDIM / KSPLIT)   // 512
#define BM     128               // rows per block (kernel 1)
#define BK     32                // K-chunk
#define NCH    (KRANGE / BK)     // 16
#define XS     162               // x LDS row stride (floats): even, %32=2 -> 2-way writes
#define WS     162               // W LDS row stride (doubles)

typedef float  f4 __attribute__((ext_vector_type(4)));
typedef float  f2 __attribute__((ext_vector_type(2)));
typedef double d2 __attribute__((ext_vector_type(2)));

// ---------------- Kernel 1: fp64 partial GEMM, K-split 4, 8x8/thread ----------
// grid 256 = 64 row-blocks x 4 K-parts; block 256 thr; 128x128 tile.
// x staged f32 [k][r'] (cvt in loop), W staged f64 [k][c'] (cvt at staging).
// r' = r + (r>>3)*2 padding: all frag reads <=2-way bank alias; x reads are
// 4-address broadcasts per wave. Inner loop: 64 dFMA + 8 cvt per k per thread.
// P values bitwise-identical to round-0 (same fp64 FMA sequence, same k order).
__global__ __launch_bounds__(256) void pkr_gemm(const float* __restrict__ x,
                                                const float* __restrict__ w1,
                                                const float* __restrict__ w2,
                                                float* __restrict__ out) {
  __shared__ float  xs[BK][XS];    // 20.7 KB
  __shared__ double wsd[BK][WS];   // 41.5 KB  (total 62.2 KB)

  const int tid   = threadIdx.x;
  const int rb    = blockIdx.x >> 2;
  const int kp    = blockIdx.x & 3;
  const int rows0 = rb * BM;
  const int kbase = kp * KRANGE;

  const int tr   = tid >> 4;      // 0..15 -> rows tr*8..+7
  const int tc   = tid & 15;      // 0..15 -> cols tc*8..+7
  const int tr10 = tr * 10;       // padded group start
  const int tc10 = tc * 10;

  // staging maps: slot s = i*256+tid -> row/col = s>>3 (0..127), kq = (s&7)*4
  int mp[4], mk[4];
  const float* xp[4];
  const float* wp[4];
#pragma unroll
  for (int i = 0; i < 4; ++i) {
    const int s  = i * 256 + tid;
    const int r  = s >> 3;
    const int kq = (s & 7) * 4;
    mp[i] = r + (r >> 3) * 2;
    mk[i] = kq;
    xp[i] = x + (size_t)(rows0 + r) * DDIM + kbase + kq;
    wp[i] = ((r < 64) ? (w1 + (size_t)r * DDIM)
                      : (w2 + (size_t)(r - 64) * DDIM)) + kbase + kq;
  }

  f4 xfr[4], wfr[4];

  auto load_regs = [&](int ch) {
    const int o = ch * BK;
#pragma unroll
    for (int i = 0; i < 4; ++i) {
      xfr[i] = *(const f4*)(xp[i] + o);
      wfr[i] = *(const f4*)(wp[i] + o);
    }
  };
  auto write_lds = [&]() {
#pragma unroll
    for (int i = 0; i < 4; ++i)
#pragma unroll
      for (int q = 0; q < 4; ++q) {
        xs[mk[i] + q][mp[i]]  = xfr[i][q];
        wsd[mk[i] + q][mp[i]] = (double)wfr[i][q];
      }
  };

  double acc[8][8] = {};

  load_regs(0);
  write_lds();
  __syncthreads();

  for (int ch = 0; ch < NCH; ++ch) {
    if (ch + 1 < NCH) load_regs(ch + 1);   // global prefetch overlaps compute
#pragma unroll 4
    for (int k = 0; k < BK; ++k) {
      double xd[8];
      d2 wd[4];
#pragma unroll
      for (int m = 0; m < 4; ++m) {
        const f2 xv = *(const f2*)&xs[k][tr10 + 2 * m];
        xd[2 * m]     = (double)xv[0];
        xd[2 * m + 1] = (double)xv[1];
        wd[m] = *(const d2*)&wsd[k][tc10 + 2 * m];
      }
#pragma unroll
      for (int a = 0; a < 8; ++a)
#pragma unroll
        for (int m = 0; m < 4; ++m) {
          acc[a][2 * m]     += xd[a] * wd[m][0];
          acc[a][2 * m + 1] += xd[a] * wd[m][1];
        }
    }
    __syncthreads();
    if (ch + 1 < NCH) {
      write_lds();
      __syncthreads();
    }
  }

  // P[row][kp*128 + col]; cols 0..63 = s1 (W1), 64..127 = s2 (W2)
  double* P = (double*)(out + (size_t)2 * NROWS * TK);
#pragma unroll
  for (int a = 0; a < 8; ++a) {
    double* dst = P + (size_t)(rows0 + tr * 8 + a) * (NEXP / 2) + kp * 128 + tc * 8;
#pragma unroll
    for (int m = 0; m < 4; ++m) {
      d2 v; v[0] = acc[a][2 * m]; v[1] = acc[a][2 * m + 1];
      *(d2*)(dst + 2 * m) = v;
    }
  }
}

// ---- branchless insert of (v,i) into sorted top-8 (val desc, idx asc) ----
__device__ __forceinline__ void ins8(double v, int i, double* av, int* ai) {
  bool b[8];
#pragma unroll
  for (int j = 0; j < 8; ++j)
    b[j] = (v > av[j]) || (v == av[j] && i < ai[j]);
#pragma unroll
  for (int j = 7; j > 0; --j) {
    av[j] = b[j] ? (b[j - 1] ? av[j - 1] : v) : av[j];
    ai[j] = b[j] ? (b[j - 1] ? ai[j - 1] : i) : ai[j];
  }
  if (b[0]) { av[0] = v; ai[0] = i; }
}

// ---------------- Kernel 2b: top8 + softmax, thread = row ----------------
// 128 blocks x 64 thr. Streams P (own row) from global; exact fp64 compares;
// semantics identical to the proven bitonic (val desc, flat idx asc on ties).
__global__ __launch_bounds__(64) void pkr_topk(float* __restrict__ out) {
  const int row = blockIdx.x * 64 + threadIdx.x;
  const double* Pr = (const double*)(out + (size_t)2 * NROWS * TK) + (size_t)row * (NEXP / 2);

  double av[8], bv[8], cv[8];
  int    ai[8], bi[8], ci[8];
#pragma unroll
  for (int t = 0; t < 8; ++t) {
    av[t] = bv[t] = cv[t] = -INFINITY;
    ai[t] = bi[t] = ci[t] = 0x7fffffff;
  }

  for (int j = 0; j < 64; ++j) {   // s1 combine (p ascending, same as expand)
    const double s = Pr[j] + Pr[128 + j] + Pr[256 + j] + Pr[384 + j];
    ins8(s, j, av, ai);
  }
  for (int j = 0; j < 64; ++j) {   // s2
    const double s = Pr[64 + j] + Pr[192 + j] + Pr[320 + j] + Pr[448 + j];
    ins8(s, j, bv, bi);
  }
#pragma unroll
  for (int p = 0; p < 8; ++p)
#pragma unroll
    for (int q = 0; q < 8; ++q)
      ins8(av[p] + bv[q], ai[p] * 64 + bi[q], cv, ci);

  float e[8], sum = 0.f;
#pragma unroll
  for (int t = 0; t < 8; ++t) { e[t] = expf((float)(cv[t] - cv[0])); sum += e[t]; }
  const float inv = 1.0f / sum;
  f4 vi0, vi1, vp0, vp1;
#pragma unroll
  for (int t = 0; t < 4; ++t) {
    vi0[t] = (float)ci[t];     vi1[t] = (float)ci[t + 4];
    vp0[t] = e[t] * inv;       vp1[t] = e[t + 4] * inv;
  }
  float* oi = out + (size_t)row * TK;
  float* op = out + (size_t)NROWS * TK + (size_t)row * TK;
  *(f4*)oi = vi0; *(f4*)(oi + 4) = vi1;
  *(f4*)op = vp0; *(f4*)(op + 4) = vp1;
}

// ---------------- Kernel 2a: combine partials + expand scores ----------------
// 4 rows per block (one wave each), 2048 blocks x 256 thr. (round-4 proven
// structure; runs AFTER pkr_topk since it overwrites P with scores.)
__global__ __launch_bounds__(256) void pkr_expand(float* __restrict__ out) {
  const int lane = threadIdx.x & 63;
  const int wv   = threadIdx.x >> 6;
  const int row  = blockIdx.x * 4 + wv;

  const double* Pr = (const double*)(out + (size_t)2 * NROWS * TK) + (size_t)row * (NEXP / 2);
  double s1 = 0.0, s2 = 0.0;
#pragma unroll
  for (int p = 0; p < KSPLIT; ++p) {
    s1 += Pr[p * 128 + lane];
    s2 += Pr[p * 128 + 64 + lane];
  }

  __shared__ double sh1[4][64], sh2[4][64];
  sh1[wv][lane] = s1;
  sh2[wv][lane] = s2;
  __syncthreads();   // memory fence: all partial reads precede slot overwrite

  float* srow = out + (size_t)2 * NROWS * TK + (size_t)row * NEXP;
  const int il = lane >> 4;          // 0..3
  const int jq = (lane & 15) * 4;    // 0..60
  const double sj0 = sh2[wv][jq + 0], sj1 = sh2[wv][jq + 1];
  const double sj2 = sh2[wv][jq + 2], sj3 = sh2[wv][jq + 3];
#pragma unroll
  for (int i0 = 0; i0 < 64; i0 += 4) {
    const double si = sh1[wv][i0 + il];
    f4 v;
    v[0] = (float)(si + sj0);
    v[1] = (float)(si + sj1);
    v[2] = (float)(si + sj2);
    v[3] = (float)(si + sj3);
    *(f4*)(srow + (size_t)(i0 + il) * 64 + jq) = v;
  }
}

extern "C" void kernel_launch(void* const* d_in, const int* in_sizes, int n_in,
                              void* d_out, int out_size, void* d_ws, size_t ws_size,
                              hipStream_t stream) {
  const float* x  = (const float*)d_in[0];
  const float* w1 = (const float*)d_in[1];
  const float* w2 = (const float*)d_in[2];
  float* out = (float*)d_out;

  hipLaunchKernelGGL(pkr_gemm, dim3((NROWS / BM) * KSPLIT), dim3(256), 0, stream,
                     x, w1, w2, out);
  hipLaunchKernelGGL(pkr_topk, dim3(NROWS / 64), dim3(64), 0, stream, out);
  hipLaunchKernelGGL(pkr_expand, dim3(NROWS / 4), dim3(256), 0, stream, out);
}

// Round 7
// 274.942 us; speedup vs baseline: 1.5809x; 1.5809x over previous
//
#include <hip/hip_runtime.h>
#include <math.h>

#define NROWS 8192
#define DDIM  2048
#define NEXP  4096
#define TK    8
#define KSPLIT 4
#define KRANGE (DDIM / KSPLIT)   // 512
#define BM     64                // rows per block (kernel 1)

typedef float  f4 __attribute__((ext_vector_type(4)));
typedef double d2 __attribute__((ext_vector_type(2)));

// ---------------- Kernel 1: fp64 partial GEMM, K-split 4, 4x8/thread ----------
// (round-5 proven: 122.5 us, VALUBusy 49%)
// grid 512 = 128 row-blocks x 4 K-parts; block 256 thr; 64x128 tile.
// Both operands staged to LDS as fp64 (cvt once at staging; inner loop pure dFMA).
// Partial P[kp] (fp64, 1KB) layout identical to round-0 (finish reader unchanged).
__global__ __launch_bounds__(256, 2) void pkr_gemm64w(const float* __restrict__ x,
                                                      const float* __restrict__ w1,
                                                      const float* __restrict__ w2,
                                                      float* __restrict__ out) {
  __shared__ double xsd[32][66];    // [k][row]  16.9 KB; row 528B (16B-aligned)
  __shared__ double wsd[32][130];   // [k][col]  33.3 KB; row 1040B (16B-aligned)

  const int tid   = threadIdx.x;
  const int rb    = blockIdx.x >> 2;
  const int kp    = blockIdx.x & 3;
  const int rows0 = rb * BM;
  const int kbase = kp * KRANGE;

  const int rh = tid >> 4;    // 0..15 -> rows rh*4..+3
  const int ch = tid & 15;    // cols g*32 + ch*2 + {0,1}

  // staging maps (coalesced f4 loads)
  const int sxr = tid >> 3;          // 0..31
  const int sxk = (tid & 7) * 4;     // 0..28
  const float* xr0 = x + (size_t)(rows0 + sxr) * DDIM + kbase + sxk;
  const float* xr1 = xr0 + (size_t)32 * DDIM;

  const int swc = tid >> 1;          // 0..127
  const int swk = (tid & 1) * 16;    // 0,16
  const float* wr = ((swc < 64) ? (w1 + (size_t)swc * DDIM)
                                : (w2 + (size_t)(swc - 64) * DDIM)) + kbase + swk;

  double acc[4][8] = {};

  for (int cch = 0; cch < KRANGE / 32; ++cch) {   // 16 chunks of K=32
    const int k0 = cch * 32;
    // ---- stage x tile (64 rows x 32 k) -> fp64 [k][row] ----
    {
      f4 a = *(const f4*)(xr0 + k0);
      f4 b = *(const f4*)(xr1 + k0);
#pragma unroll
      for (int q = 0; q < 4; ++q) {
        xsd[sxk + q][sxr]      = (double)a[q];
        xsd[sxk + q][32 + sxr] = (double)b[q];
      }
    }
    // ---- stage W tile (128 cols x 32 k) -> fp64 [k][col] (cvt once here) ----
#pragma unroll
    for (int p = 0; p < 4; ++p) {
      f4 wv = *(const f4*)(wr + k0 + p * 4);
#pragma unroll
      for (int q = 0; q < 4; ++q)
        wsd[swk + p * 4 + q][swc] = (double)wv[q];
    }
    __syncthreads();

#pragma unroll
    for (int k = 0; k < 32; ++k) {
      const d2 x01 = *(const d2*)&xsd[k][rh * 4];       // broadcast within wave
      const d2 x23 = *(const d2*)&xsd[k][rh * 4 + 2];
      const double xd[4] = { x01[0], x01[1], x23[0], x23[1] };
      d2 wg[4];
#pragma unroll
      for (int g = 0; g < 4; ++g) wg[g] = *(const d2*)&wsd[k][g * 32 + ch * 2];
#pragma unroll
      for (int a = 0; a < 4; ++a)
#pragma unroll
        for (int g = 0; g < 4; ++g) {
          acc[a][2 * g]     += xd[a] * wg[g][0];
          acc[a][2 * g + 1] += xd[a] * wg[g][1];
        }
    }
    __syncthreads();
  }

  // P[row][kp*128 + g*32 + ch*2 + {0,1}] ; cols 0..63 = s1 (W1), 64..127 = s2 (W2)
  double* P = (double*)(out + (size_t)2 * NROWS * TK);
#pragma unroll
  for (int a = 0; a < 4; ++a) {
    double* dst = P + (size_t)(rows0 + rh * 4 + a) * (NEXP / 2) + kp * 128;
#pragma unroll
    for (int g = 0; g < 4; ++g) {
      d2 v; v[0] = acc[a][2 * g]; v[1] = acc[a][2 * g + 1];
      *(d2*)(dst + g * 32 + ch * 2) = v;
    }
  }
}

// ---- bitonic sort of 64 lanes, best-first; order: (val desc, idx asc) ----
__device__ __forceinline__ void bitonic64(double& v, int& idx, int lane) {
#pragma unroll
  for (int k = 2; k <= 64; k <<= 1) {
#pragma unroll
    for (int j = k >> 1; j > 0; j >>= 1) {
      const double ov = __shfl_xor(v, j);
      const int    oi = __shfl_xor(idx, j);
      const bool obetter = (ov > v) || (ov == v && oi < idx);
      const bool lower   = (lane & j) == 0;
      const bool up      = (lane & k) == 0;   // best-first segment
      if ((lower == up) ? obetter : !obetter) { v = ov; idx = oi; }
    }
  }
}

// ---------------- Kernel 2: combine partials + expand + top8 + softmax ----------
// 4 rows per block (one wave each), 2048 blocks x 256 thr. (round-4 proven,
// + nontemporal scores stores: the 128MB stream is never re-read.)
__global__ __launch_bounds__(256) void pkr_finish(float* __restrict__ out) {
  const int lane = threadIdx.x & 63;
  const int wv   = threadIdx.x >> 6;
  const int row  = blockIdx.x * 4 + wv;

  const double* Pr = (const double*)(out + (size_t)2 * NROWS * TK) + (size_t)row * (NEXP / 2);
  double s1 = 0.0, s2 = 0.0;
#pragma unroll
  for (int p = 0; p < KSPLIT; ++p) {
    s1 += Pr[p * 128 + lane];
    s2 += Pr[p * 128 + 64 + lane];
  }

  __shared__ double sh1[4][64], sh2[4][64];
  sh1[wv][lane] = s1;
  sh2[wv][lane] = s2;
  __syncthreads();   // memory fence: all partial reads precede slot overwrite

  // ---- scores[row][i*64+j] = float(s1[i] + s2[j]), 1KB contiguous per instr ----
  {
    float* srow = out + (size_t)2 * NROWS * TK + (size_t)row * NEXP;
    const int il = lane >> 4;          // 0..3
    const int jq = (lane & 15) * 4;    // 0..60
    const double sj0 = sh2[wv][jq + 0], sj1 = sh2[wv][jq + 1];
    const double sj2 = sh2[wv][jq + 2], sj3 = sh2[wv][jq + 3];
#pragma unroll
    for (int i0 = 0; i0 < 64; i0 += 4) {
      const double si = sh1[wv][i0 + il];
      f4 v;
      v[0] = (float)(si + sj0);
      v[1] = (float)(si + sj1);
      v[2] = (float)(si + sj2);
      v[3] = (float)(si + sj3);
      __builtin_nontemporal_store(v, (f4*)(srow + (size_t)(i0 + il) * 64 + jq));
    }
  }

  // ---- top8 of s1 and s2 via full bitonic sort (tie-break: idx asc) ----
  double v1 = s1; int i1 = lane;
  bitonic64(v1, i1, lane);
  double v2 = s2; int i2 = lane;
  bitonic64(v2, i2, lane);

  // ---- 64 candidate sums (top8 x top8), top8 by (val desc, flat idx asc) ----
  const double ca = __shfl(v1, lane >> 3);
  const int    ia = __shfl(i1, lane >> 3);
  const double cb = __shfl(v2, lane & 7);
  const int    ib = __shfl(i2, lane & 7);
  double cv = ca + cb;
  int    ci = ia * 64 + ib;
  bitonic64(cv, ci, lane);

  // ---- softmax over lanes 0..7 + emit ----
  const double vmax = __shfl(cv, 0);
  float e = expf((float)(cv - vmax));
  float sum = e;
#pragma unroll
  for (int off = 1; off < 8; off <<= 1) sum += __shfl_xor(sum, off);  // 8-group sum
  if (lane < 8) {
    out[(size_t)row * TK + lane]                      = (float)ci;
    out[(size_t)NROWS * TK + (size_t)row * TK + lane] = e / sum;
  }
}

extern "C" void kernel_launch(void* const* d_in, const int* in_sizes, int n_in,
                              void* d_out, int out_size, void* d_ws, size_t ws_size,
                              hipStream_t stream) {
  const float* x  = (const float*)d_in[0];
  const float* w1 = (const float*)d_in[1];
  const float* w2 = (const float*)d_in[2];
  float* out = (float*)d_out;

  hipLaunchKernelGGL(pkr_gemm64w, dim3((NROWS / BM) * KSPLIT), dim3(256), 0, stream,
                     x, w1, w2, out);
  hipLaunchKernelGGL(pkr_finish, dim3(NROWS / 4), dim3(256), 0, stream, out);
}

// Round 9
// 272.494 us; speedup vs baseline: 1.5951x; 1.0090x over previous
//
#include <hip/hip_runtime.h>
#include <math.h>

#define NROWS 8192
#define DDIM  2048
#define NEXP  4096
#define TK    8
#define BM    32                 // rows per block (kernel 1)
#define BK    32                 // K-chunk
#define NCH   (DDIM / BK)        // 64

typedef float  f4    __attribute__((ext_vector_type(4)));
typedef double d2    __attribute__((ext_vector_type(2)));
typedef double f64x4 __attribute__((ext_vector_type(4)));

// ---- shuffle-emulated 16x16x4 fp64 MFMA (self-consistent reference) ----
// Convention L1: A: lane = m + 16k; B: lane = n + 16k; D: row=4*(l>>4)+e, col=l&15.
__device__ __forceinline__ f64x4 mfma_emu(double a, double b, f64x4 c) {
  const int l = threadIdx.x & 63;
  f64x4 d = c;
#pragma unroll
  for (int e = 0; e < 4; ++e) {
    const int m = (l >> 4) * 4 + e;
    double s = 0.0;
#pragma unroll
    for (int k = 0; k < 4; ++k)
      s += __shfl(a, m + 16 * k) * __shfl(b, (l & 15) + 16 * k);
    d[e] += s;
  }
  return d;
}

__device__ __forceinline__ f64x4 mfma_hw(double a, double b, f64x4 c) {
#if __has_builtin(__builtin_amdgcn_mfma_f64_16x16x4f64)
  return __builtin_amdgcn_mfma_f64_16x16x4f64(a, b, c, 0, 0, 0);
#else
  return mfma_emu(a, b, c);
#endif
}

// ---------------- Kernel 1: full-K fp64 MFMA GEMM, self-calibrating ----------
// grid 256 row-blocks; block 256 thr (4 waves). Tile 32 rows x 128 cols.
// Wave wv: row-tile rt=wv&1 (16 rows), col-half cq=wv>>1 (4 MFMA col-tiles).
// Runtime probes decode the REAL operand/result lane layouts (L1: idx = m+16k,
// or L2: idx = 4m+k) and the true D positions; store uses decoded (dm,dn).
// If decode fails sanity, falls back to the self-consistent emu path (correct).
__global__ __launch_bounds__(256) void pkr_gemm_mfma(const float* __restrict__ x,
                                                     const float* __restrict__ w1,
                                                     const float* __restrict__ w2,
                                                     float* __restrict__ out) {
  __shared__ double xsd[BM][34];     // [row][k]   8.5 KB
  __shared__ double wsd[128][34];    // [col][k]  34.8 KB   (total 43.3 KB)

  const int tid   = threadIdx.x;
  const int rows0 = blockIdx.x * BM;

  const int lane = tid & 63;
  const int wv   = tid >> 6;
  const int fr   = lane & 15;
  const int fk   = lane >> 4;
  const int rt   = wv & 1;      // row-tile  (rows rt*16 .. +15)
  const int cq   = wv >> 1;     // col-half  (cols cq*64 .. +63)

  // ---- calibration probes (layout-agnostic) ----
  // accA[e] = sum_k A_hw[m][k] with A fed lane-index values:
  //   L1 (lane=m+16k): value = 4m+96 (mod4==0);  L2 (lane=4m+k): 16m+6 (mod4==2)
  f64x4 zz = {};
  const double pl = (double)lane;
  const f64x4 accA = mfma_hw(pl, 1.0, zz);
  const f64x4 accB = mfma_hw(1.0, pl, zz);

  const int vA0 = (int)accA[0];
  const int vB0 = (int)accB[0];
  const bool aL1 = ((vA0 & 3) == 0);
  const bool bL1 = ((vB0 & 3) == 0);
  int dm[4], dn[4];
  bool okl = true;
#pragma unroll
  for (int e = 0; e < 4; ++e) {
    const int va = (int)accA[e];
    const int vb = (int)accB[e];
    const int me = aL1 ? ((va - 96) >> 2) : ((va - 6) >> 4);
    const int ne = bL1 ? ((vb - 96) >> 2) : ((vb - 6) >> 4);
    okl = okl && (me >= 0) && (me < 16) && (ne >= 0) && (ne < 16);
    okl = okl && (va == (aL1 ? 96 + 4 * me : 6 + 16 * me));
    okl = okl && (vb == (bL1 ? 96 + 4 * ne : 6 + 16 * ne));
    dm[e] = me & 15;
    dn[e] = ne & 15;
  }
  okl = okl && (dm[0] != dm[1]) && (dm[0] != dm[2]) && (dm[0] != dm[3]) &&
               (dm[1] != dm[2]) && (dm[1] != dm[3]) && (dm[2] != dm[3]);
  const bool calib_ok = (__all((int)okl) != 0);

  // feed indices per decoded input layout
  const int am = aL1 ? fr : (lane >> 2);
  const int ak = aL1 ? fk : (lane & 3);
  const int bn = bL1 ? fr : (lane >> 2);
  const int bk = bL1 ? fk : (lane & 3);

  // staging maps (coalesced f4 global loads)
  const int xr = tid >> 3;             // 0..31 row, 8 thr/row
  const int xk = (tid & 7) * 4;        // 0,4,...,28
  const int wc = tid >> 1;             // 0..127 col, 2 thr/col
  const int wk = (tid & 1) * 16;       // 0,16
  const float* xrow = x + (size_t)(rows0 + xr) * DDIM + xk;
  const float* wrow = ((wc < 64) ? (w1 + (size_t)wc * DDIM)
                                 : (w2 + (size_t)(wc - 64) * DDIM)) + wk;

  f4 xf, wf[4];

#define LOAD_REGS(CH) do {                                        \
    const int o_ = (CH) * BK;                                     \
    xf    = *(const f4*)(xrow + o_);                              \
    wf[0] = *(const f4*)(wrow + o_);                              \
    wf[1] = *(const f4*)(wrow + o_ + 4);                          \
    wf[2] = *(const f4*)(wrow + o_ + 8);                          \
    wf[3] = *(const f4*)(wrow + o_ + 12);                         \
  } while (0)

#define WRITE_LDS() do {                                          \
    d2 t_;                                                        \
    t_[0] = (double)xf[0]; t_[1] = (double)xf[1];                 \
    *(d2*)&xsd[xr][xk]     = t_;                                  \
    t_[0] = (double)xf[2]; t_[1] = (double)xf[3];                 \
    *(d2*)&xsd[xr][xk + 2] = t_;                                  \
    _Pragma("unroll")                                             \
    for (int p_ = 0; p_ < 4; ++p_) {                              \
      t_[0] = (double)wf[p_][0]; t_[1] = (double)wf[p_][1];       \
      *(d2*)&wsd[wc][wk + p_ * 4]     = t_;                       \
      t_[0] = (double)wf[p_][2]; t_[1] = (double)wf[p_][3];       \
      *(d2*)&wsd[wc][wk + p_ * 4 + 2] = t_;                       \
    }                                                             \
  } while (0)

#define GEMM_LOOP(MFMA_CALL, AM, AK, BN, BKI)                              \
    LOAD_REGS(0);                                                          \
    WRITE_LDS();                                                           \
    __syncthreads();                                                       \
    for (int ch = 0; ch < NCH; ++ch) {                                     \
      if (ch + 1 < NCH) LOAD_REGS(ch + 1);                                 \
      _Pragma("unroll")                                                    \
      for (int ks = 0; ks < BK / 4; ++ks) {                                \
        const double a = xsd[rt * 16 + (AM)][ks * 4 + (AK)];               \
        _Pragma("unroll")                                                  \
        for (int c = 0; c < 4; ++c) {                                      \
          const double b = wsd[cq * 64 + c * 16 + (BN)][ks * 4 + (BKI)];   \
          acc[c] = MFMA_CALL(a, b, acc[c]);                                \
        }                                                                  \
      }                                                                    \
      __syncthreads();                                                     \
      if (ch + 1 < NCH) { WRITE_LDS(); __syncthreads(); }                  \
    }

  double* P = (double*)(out + (size_t)2 * NROWS * TK);

  if (calib_ok) {
    f64x4 acc[4] = {};
    GEMM_LOOP(mfma_hw, am, ak, bn, bk)
#pragma unroll
    for (int c = 0; c < 4; ++c)
#pragma unroll
      for (int e = 0; e < 4; ++e) {
        const int row = rows0 + rt * 16 + dm[e];
        const int col = cq * 64 + c * 16 + dn[e];
        P[(size_t)row * (NEXP / 2) + col] = acc[c][e];
      }
  } else {
    f64x4 acc[4] = {};
    GEMM_LOOP(mfma_emu, fr, fk, fr, fk)
#pragma unroll
    for (int c = 0; c < 4; ++c)
#pragma unroll
      for (int e = 0; e < 4; ++e) {
        const int row = rows0 + rt * 16 + fk * 4 + e;
        const int col = cq * 64 + c * 16 + fr;
        P[(size_t)row * (NEXP / 2) + col] = acc[c][e];
      }
  }
#undef GEMM_LOOP
#undef LOAD_REGS
#undef WRITE_LDS
}

// ---- bitonic sort of 64 lanes, best-first; order: (val desc, idx asc) ----
__device__ __forceinline__ void bitonic64(double& v, int& idx, int lane) {
#pragma unroll
  for (int k = 2; k <= 64; k <<= 1) {
#pragma unroll
    for (int j = k >> 1; j > 0; j >>= 1) {
      const double ov = __shfl_xor(v, j);
      const int    oi = __shfl_xor(idx, j);
      const bool obetter = (ov > v) || (ov == v && oi < idx);
      const bool lower   = (lane & j) == 0;
      const bool up      = (lane & k) == 0;   // best-first segment
      if ((lower == up) ? obetter : !obetter) { v = ov; idx = oi; }
    }
  }
}

// ---------------- Kernel 2: expand + top8 + softmax ----------------
// 4 rows per block (one wave each), 2048 blocks x 256 thr.  (round-4 proven
// body; full-K P read — no partial combine.)
__global__ __launch_bounds__(256) void pkr_finish(float* __restrict__ out) {
  const int lane = threadIdx.x & 63;
  const int wv   = threadIdx.x >> 6;
  const int row  = blockIdx.x * 4 + wv;

  const double* Pr = (const double*)(out + (size_t)2 * NROWS * TK) + (size_t)row * (NEXP / 2);
  const double s1 = Pr[lane];
  const double s2 = Pr[64 + lane];

  __shared__ double sh1[4][64], sh2[4][64];
  sh1[wv][lane] = s1;
  sh2[wv][lane] = s2;
  __syncthreads();   // memory fence: all P reads precede slot overwrite

  // ---- scores[row][i*64+j] = float(s1[i] + s2[j]), 1KB contiguous per instr ----
  {
    float* srow = out + (size_t)2 * NROWS * TK + (size_t)row * NEXP;
    const int il = lane >> 4;          // 0..3
    const int jq = (lane & 15) * 4;    // 0..60
    const double sj0 = sh2[wv][jq + 0], sj1 = sh2[wv][jq + 1];
    const double sj2 = sh2[wv][jq + 2], sj3 = sh2[wv][jq + 3];
#pragma unroll
    for (int i0 = 0; i0 < 64; i0 += 4) {
      const double si = sh1[wv][i0 + il];
      f4 v;
      v[0] = (float)(si + sj0);
      v[1] = (float)(si + sj1);
      v[2] = (float)(si + sj2);
      v[3] = (float)(si + sj3);
      *(f4*)(srow + (size_t)(i0 + il) * 64 + jq) = v;
    }
  }

  // ---- top8 of s1 and s2 via full bitonic sort (tie-break: idx asc) ----
  double v1 = s1; int i1 = lane;
  bitonic64(v1, i1, lane);
  double v2 = s2; int i2 = lane;
  bitonic64(v2, i2, lane);

  // ---- 64 candidate sums (top8 x top8), top8 by (val desc, flat idx asc) ----
  const double ca = __shfl(v1, lane >> 3);
  const int    ia = __shfl(i1, lane >> 3);
  const double cb = __shfl(v2, lane & 7);
  const int    ib = __shfl(i2, lane & 7);
  double cv = ca + cb;
  int    ci = ia * 64 + ib;
  bitonic64(cv, ci, lane);

  // ---- softmax over lanes 0..7 + emit ----
  const double vmax = __shfl(cv, 0);
  float e = expf((float)(cv - vmax));
  float sum = e;
#pragma unroll
  for (int off = 1; off < 8; off <<= 1) sum += __shfl_xor(sum, off);  // 8-group sum
  if (lane < 8) {
    out[(size_t)row * TK + lane]                      = (float)ci;
    out[(size_t)NROWS * TK + (size_t)row * TK + lane] = e / sum;
  }
}

extern "C" void kernel_launch(void* const* d_in, const int* in_sizes, int n_in,
                              void* d_out, int out_size, void* d_ws, size_t ws_size,
                              hipStream_t stream) {
  const float* x  = (const float*)d_in[0];
  const float* w1 = (const float*)d_in[1];
  const float* w2 = (const float*)d_in[2];
  float* out = (float*)d_out;

  hipLaunchKernelGGL(pkr_gemm_mfma, dim3(NROWS / BM), dim3(256), 0, stream,
                     x, w1, w2, out);
  hipLaunchKernelGGL(pkr_finish, dim3(NROWS / 4), dim3(256), 0, stream, out);
}